// Round 5
// baseline (547.535 us; speedup 1.0000x reference)
//
#include <hip/hip_runtime.h>
#include <math.h>

#define BB 8
#define TT 4096
#define DDIM 512
#define KK 4096
#define NN (BB*TT)
#define EPS 0.05f

typedef __attribute__((ext_vector_type(8))) short bf16x8;
typedef __attribute__((ext_vector_type(4))) float f32x4;

__device__ __forceinline__ void async16(void* lds, const void* g) {
  __builtin_amdgcn_global_load_lds((const __attribute__((address_space(1))) void*)g,
                                   (__attribute__((address_space(3))) void*)lds, 16, 0, 0);
}

__device__ __forceinline__ unsigned pk_bf16(float a, float b) {
  unsigned ua = __float_as_uint(a); ua += 0x7FFFu + ((ua >> 16) & 1u);
  unsigned ub = __float_as_uint(b); ub += 0x7FFFu + ((ub >> 16) & 1u);
  return (ua >> 16) | (ub & 0xFFFF0000u);
}

// ---------- prep: row sum-sq (esq or inv2=2/norm) + bf16 (RTNE) conversion ----------
__global__ __launch_bounds__(256) void prep_kernel(const float* __restrict__ src,
                                                   short* __restrict__ dst16,
                                                   float* __restrict__ outv, int mode) {
  int r = blockIdx.x * 4 + (threadIdx.x >> 6);
  int lane = threadIdx.x & 63;
  const float4* row4 = (const float4*)(src + (size_t)r * DDIM);
  float4 v0 = row4[lane];
  float4 v1 = row4[lane + 64];
  uint2 p0, p1;
  p0.x = pk_bf16(v0.x, v0.y); p0.y = pk_bf16(v0.z, v0.w);
  p1.x = pk_bf16(v1.x, v1.y); p1.y = pk_bf16(v1.z, v1.w);
  *(uint2*)(dst16 + (size_t)r * DDIM + lane * 4) = p0;
  *(uint2*)(dst16 + (size_t)r * DDIM + 256 + lane * 4) = p1;
  float ss = v0.x*v0.x + v0.y*v0.y + v0.z*v0.z + v0.w*v0.w
           + v1.x*v1.x + v1.y*v1.y + v1.z*v1.z + v1.w*v1.w;
  #pragma unroll
  for (int off = 32; off; off >>= 1) ss += __shfl_down(ss, off);
  if (lane == 0) outv[r] = mode ? 2.0f / fmaxf(sqrtf(ss), 1e-12f) : ss;
}

// ---------- main MFMA pass: A-resident LDS, B L2->regs, PACED, 16 waves ----------
// 256 blocks (1/CU), 1024 threads = 16 waves (2 row-halves x 8 code-eighths).
// Same per-wave body as round 4 (4 A-frags LDS / 4 B-frags global / 16 MFMA /
// depth-1 B prefetch) but 4 waves/SIMD instead of 2: wave interleaving covers
// L2 and LDS latency (round-4 counters: all pipes <25% busy simultaneously =
// latency-bound at 2 waves/SIMD). A (128x512 bf16, 128 KiB) staged once.
// One raw s_barrier per 512-code tile (pacing only, loads stay in flight):
// keeps all blocks on the same codebook window -> L2-resident B (r4: 33 MB).
__global__ __launch_bounds__(1024, 4) void vq_mfma(const short* __restrict__ xb,
                                                   const short* __restrict__ eb,
                                                   const float* __restrict__ esq,
                                                   const float* __restrict__ inv2,
                                                   float* __restrict__ out_ind,
                                                   int* __restrict__ flags,
                                                   int* __restrict__ list,
                                                   int* __restrict__ cnt) {
  __shared__ __attribute__((aligned(16))) short As[128 * 512];   // 131072 B
  __shared__ float rS1[8][128];
  __shared__ float rS2[8][128];
  __shared__ int   rI1[8][128];

  const int tid = threadIdx.x;
  const int lane = tid & 63;
  const int w = tid >> 6;          // 0..15
  const int wr = w >> 3;           // row half (0..1): rows wr*64..+64
  const int wc = w & 7;            // code eighth within each 512-code tile
  const int q = lane >> 4, c16 = lane & 15;
  const int n0 = blockIdx.x * 128;

  // ---- A stage (once): wave w stages rows j*16+w (j=0..7); physical 16B-chunk
  // `lane` holds global chunk lane^(w&7)  (per-row XOR swizzle by row&7)
  #pragma unroll
  for (int j = 0; j < 8; ++j)
    async16(As + (j * 16 + w) * 512,
            xb + (size_t)(n0 + j * 16 + w) * 512 + (lane ^ (w & 7)) * 8);

  const int arow0 = (wr * 64 + c16) * 512;   // + ti*8192 + ach (shorts)

  // B global fragment base: code (col) = wc*64 + c16, k-chunk = q (8 dims, 16B).
  // Full addr adds ct*512*512 + tj*16*512 + s*32 (shorts).
  const short* gB = eb + (size_t)(wc * 64 + c16) * DDIM + q * 8;

  // inv2 values for my 16 row-slots (regs for whole kernel)
  f32x4 iv4[4];
  #pragma unroll
  for (int ti = 0; ti < 4; ++ti)
    iv4[ti] = *(const f32x4*)&inv2[n0 + wr * 64 + ti * 16 + q * 4];

  float s1[16], s2v[16];
  int   i1[16];
  #pragma unroll
  for (int s = 0; s < 16; ++s) { s1[s] = -3e38f; s2v[s] = -3e38f; i1[s] = 0; }

  // prefetch B fragments for (ct=0, s=0) before waiting on A
  bf16x8 bfc[4];
  #pragma unroll
  for (int tj = 0; tj < 4; ++tj)
    bfc[tj] = *(const bf16x8*)(gB + (size_t)tj * 16 * DDIM);

  __syncthreads();   // A landed (vmcnt(0) drain happens once, here only)

  for (int ct = 0; ct < 8; ++ct) {
    const short* gBc = gB + (size_t)ct * 512 * DDIM;
    // uniform base for the cross-ct prefetch (clamped at the last tile)
    const short* gBn_ct = (ct < 7) ? gBc + 512 * DDIM : gBc;
    float nes[4];
    #pragma unroll
    for (int tj = 0; tj < 4; ++tj)
      nes[tj] = -esq[ct * 512 + wc * 64 + tj * 16 + c16];
    f32x4 acc[4][4];
    #pragma unroll
    for (int ti = 0; ti < 4; ++ti)
      #pragma unroll
      for (int tj = 0; tj < 4; ++tj) acc[ti][tj] = (f32x4){0.f, 0.f, 0.f, 0.f};

    #pragma unroll
    for (int s = 0; s < 16; ++s) {
      // issue next step's B loads first (longest latency, covered by MFMAs)
      bf16x8 bfn[4];
      const short* gBn = (s < 15) ? (gBc + (s + 1) * 32) : gBn_ct;
      #pragma unroll
      for (int tj = 0; tj < 4; ++tj)
        bfn[tj] = *(const bf16x8*)(gBn + (size_t)tj * 16 * DDIM);
      // A fragments from LDS (swizzled)
      const int ach = ((s * 4 + q) ^ (c16 & 7)) * 8;
      bf16x8 af[4];
      #pragma unroll
      for (int ti = 0; ti < 4; ++ti)
        af[ti] = *(const bf16x8*)(As + arow0 + ti * 8192 + ach);
      __builtin_amdgcn_s_setprio(1);
      #pragma unroll
      for (int ti = 0; ti < 4; ++ti)
        #pragma unroll
        for (int tj = 0; tj < 4; ++tj)
          acc[ti][tj] = __builtin_amdgcn_mfma_f32_16x16x32_bf16(af[ti], bfc[tj], acc[ti][tj], 0, 0, 0);
      __builtin_amdgcn_s_setprio(0);
      #pragma unroll
      for (int tj = 0; tj < 4; ++tj) bfc[tj] = bfn[tj];
    }

    // ---------- epilogue for this 512-code tile (registers only) ----------
    // (also covers the latency of the already-issued next-ct B prefetch)
    const int colbase = ct * 512 + wc * 64 + c16;
    #pragma unroll
    for (int ti = 0; ti < 4; ++ti)
      #pragma unroll
      for (int r = 0; r < 4; ++r) {
        const int slot = ti * 4 + r;
        const float iv = iv4[ti][r];
        #pragma unroll
        for (int tj = 0; tj < 4; ++tj) {
          float sc = fmaf(acc[ti][tj][r], iv, nes[tj]);
          float mn = fminf(sc, s1[slot]);
          s2v[slot] = fmaxf(s2v[slot], mn);
          if (sc > s1[slot]) { s1[slot] = sc; i1[slot] = colbase + tj * 16; }
        }
      }

    // pacing barrier: raw s_barrier, NO waitcnt drain (A read-only, B in regs).
    __builtin_amdgcn_s_barrier();
  }

  // ---------- final merge: 16 lanes -> 8 wc-waves -> write results ----------
  #pragma unroll
  for (int slot = 0; slot < 16; ++slot) {
    float a1 = s1[slot], a2 = s2v[slot]; int ai = i1[slot];
    #pragma unroll
    for (int off = 1; off < 16; off <<= 1) {
      float b1 = __shfl_xor(a1, off);
      float b2 = __shfl_xor(a2, off);
      int   bi = __shfl_xor(ai, off);
      float mn = fminf(a1, b1);
      a2 = fmaxf(fmaxf(a2, b2), mn);
      if (b1 > a1 || (b1 == a1 && bi < ai)) { a1 = b1; ai = bi; }
    }
    if (c16 == 0) {
      int row = wr * 64 + (slot >> 2) * 16 + q * 4 + (slot & 3);
      rS1[wc][row] = a1; rS2[wc][row] = a2; rI1[wc][row] = ai;
    }
  }
  __syncthreads();
  if (tid < 128) {
    float a1 = rS1[0][tid], a2 = rS2[0][tid]; int ai = rI1[0][tid];
    #pragma unroll
    for (int gq = 1; gq < 8; ++gq) {
      float b1 = rS1[gq][tid], b2 = rS2[gq][tid]; int bi = rI1[gq][tid];
      float mn = fminf(a1, b1);
      a2 = fmaxf(fmaxf(a2, b2), mn);
      if (b1 > a1 || (b1 == a1 && bi < ai)) { a1 = b1; ai = bi; }
    }
    const int row = n0 + tid;
    out_ind[row] = (float)ai;
    if (a1 - a2 < EPS) {
      int p = atomicAdd(cnt, 1);
      list[p] = row;
      flags[row] = p + 1;
    } else {
      flags[row] = 0;
    }
  }
}

// ---------- cleanup: exact fp32 rescore of flagged rows (split 8 k-chunks) ----------
__global__ __launch_bounds__(256) void cleanup_kernel(const float* __restrict__ x,
                                                      const float* __restrict__ embed,
                                                      const float* __restrict__ esq,
                                                      const float* __restrict__ inv2,
                                                      const int* __restrict__ list,
                                                      const int* __restrict__ cnt,
                                                      float2* __restrict__ exact) {
  __shared__ float xr[DDIM];
  __shared__ float red_s[4];
  __shared__ int   red_i[4];
  const int rs = blockIdx.x & 31, kc = blockIdx.x >> 5;
  const int tid = threadIdx.x;
  const int lane = tid & 63, wid = tid >> 6;
  const int n = *cnt;
  for (int ii = rs; ii < n; ii += 32) {
    const int row = list[ii];
    __syncthreads();
    if (tid < 128) *(float4*)&xr[tid * 4] = *(const float4*)&x[(size_t)row * DDIM + tid * 4];
    __syncthreads();
    const float iv = inv2[row];
    float bs = -3e38f; int bi = 0;
    for (int cc = 0; cc < 2; ++cc) {
      const int code = kc * 512 + cc * 256 + tid;
      const float4* er = (const float4*)&embed[(size_t)code * DDIM];
      float acc = 0.f;
      for (int d = 0; d < DDIM / 4; ++d) {
        float4 e4 = er[d];
        float4 x4 = *(const float4*)&xr[d * 4];
        acc += x4.x * e4.x + x4.y * e4.y + x4.z * e4.z + x4.w * e4.w;
      }
      float sc = fmaf(acc, iv, -esq[code]);
      if (sc > bs || (sc == bs && code < bi)) { bs = sc; bi = code; }
    }
    #pragma unroll
    for (int off = 1; off < 64; off <<= 1) {
      float b1 = __shfl_xor(bs, off);
      int   b2 = __shfl_xor(bi, off);
      if (b1 > bs || (b1 == bs && b2 < bi)) { bs = b1; bi = b2; }
    }
    if (lane == 0) { red_s[wid] = bs; red_i[wid] = bi; }
    __syncthreads();
    if (tid == 0) {
      for (int ww = 1; ww < 4; ++ww)
        if (red_s[ww] > red_s[0] || (red_s[ww] == red_s[0] && red_i[ww] < red_i[0])) {
          red_s[0] = red_s[ww]; red_i[0] = red_i[ww];
        }
      exact[(size_t)ii * 8 + kc] = make_float2(red_s[0], (float)red_i[0]);
    }
  }
}

// ---------- gather + transpose (merges exact results for flagged rows) ----------
__global__ __launch_bounds__(256) void gather_kernel(const float* __restrict__ embed,
                                                     const int* __restrict__ flags,
                                                     const float2* __restrict__ exact,
                                                     float* __restrict__ out_ind,
                                                     float* __restrict__ out_q) {
  __shared__ int lidx[64];
  __shared__ float trans[64 * 65];
  const int n0 = blockIdx.x * 64;
  const int tid = threadIdx.x;
  if (tid < 64) {
    const int row = n0 + tid;
    const int f = flags[row];
    int idx;
    if (f) {
      float bsv = -3e38f; int bi = 0;
      const float2* e8 = &exact[(size_t)(f - 1) * 8];
      #pragma unroll
      for (int k = 0; k < 8; ++k) {
        float2 t = e8[k];
        int ci = (int)t.y;
        if (t.x > bsv || (t.x == bsv && ci < bi)) { bsv = t.x; bi = ci; }
      }
      idx = bi;
      out_ind[row] = (float)idx;
    } else {
      idx = (int)out_ind[row];
    }
    lidx[tid] = idx;
  }
  __syncthreads();
  const int bb = n0 >> 12;
  const int t0 = n0 & (TT - 1);
  const int w = tid >> 6, lane = tid & 63;
  for (int d0 = 0; d0 < DDIM; d0 += 64) {
    if (d0) __syncthreads();
    #pragma unroll
    for (int qq = 0; qq < 16; ++qq) {
      int tt2 = w * 16 + qq;
      int e = lidx[tt2];
      trans[lane * 65 + tt2] = embed[(size_t)e * DDIM + d0 + lane];
    }
    __syncthreads();
    #pragma unroll
    for (int qq = 0; qq < 4; ++qq) {
      int dl = (tid >> 4) * 4 + qq;
      int t4 = (tid & 15) * 4;
      float4 o;
      o.x = trans[dl * 65 + t4 + 0];
      o.y = trans[dl * 65 + t4 + 1];
      o.z = trans[dl * 65 + t4 + 2];
      o.w = trans[dl * 65 + t4 + 3];
      *(float4*)&out_q[((size_t)bb * DDIM + d0 + dl) * TT + t0 + t4] = o;
    }
  }
}

extern "C" void kernel_launch(void* const* d_in, const int* in_sizes, int n_in,
                              void* d_out, int out_size, void* d_ws, size_t ws_size,
                              hipStream_t stream) {
  const float* x     = (const float*)d_in[0];
  const float* embed = (const float*)d_in[1];
  char* ws = (char*)d_ws;
  short* xb      = (short*)(ws);                         // 33,554,432 B
  short* eb      = (short*)(ws + 33554432);              //  4,194,304 B
  float* esq     = (float*)(ws + 37748736);              //     16,384 B
  float* inv2    = (float*)(ws + 37765120);              //    131,072 B
  int* list      = (int*)(ws + 39993344);                //    131,072 B
  int* flags     = (int*)(ws + 40124416);                //    131,072 B
  float2* exact  = (float2*)(ws + 40255488);             //  2,097,152 B
  int* cnt       = (int*)(ws + 42352640);                //          4 B

  float* out_ind = (float*)d_out;
  float* out_q   = out_ind + NN;

  prep_kernel<<<KK / 4, 256, 0, stream>>>(embed, eb, esq, 0);
  prep_kernel<<<NN / 4, 256, 0, stream>>>(x, xb, inv2, 1);
  hipMemsetAsync(cnt, 0, 4, stream);
  vq_mfma<<<256, 1024, 0, stream>>>(xb, eb, esq, inv2, out_ind, flags, list, cnt);
  cleanup_kernel<<<256, 256, 0, stream>>>(x, embed, esq, inv2, list, cnt, exact);
  gather_kernel<<<NN / 64, 256, 0, stream>>>(embed, flags, exact, out_ind, out_q);
}

// Round 7
// 411.022 us; speedup vs baseline: 1.3321x; 1.3321x over previous
//
#include <hip/hip_runtime.h>
#include <math.h>

#define BB 8
#define TT 4096
#define DDIM 512
#define KK 4096
#define NN (BB*TT)
#define EPS 0.05f

typedef __attribute__((ext_vector_type(8))) short bf16x8;
typedef __attribute__((ext_vector_type(4))) float f32x4;

__device__ __forceinline__ void async16(void* lds, const void* g) {
  __builtin_amdgcn_global_load_lds((const __attribute__((address_space(1))) void*)g,
                                   (__attribute__((address_space(3))) void*)lds, 16, 0, 0);
}

__device__ __forceinline__ unsigned pk_bf16(float a, float b) {
  unsigned ua = __float_as_uint(a); ua += 0x7FFFu + ((ua >> 16) & 1u);
  unsigned ub = __float_as_uint(b); ub += 0x7FFFu + ((ub >> 16) & 1u);
  return (ua >> 16) | (ub & 0xFFFF0000u);
}

// ---------- prep: row sum-sq (esq or inv2=2/norm) + bf16 (RTNE) conversion ----------
__global__ __launch_bounds__(256) void prep_kernel(const float* __restrict__ src,
                                                   short* __restrict__ dst16,
                                                   float* __restrict__ outv, int mode) {
  int r = blockIdx.x * 4 + (threadIdx.x >> 6);
  int lane = threadIdx.x & 63;
  const float4* row4 = (const float4*)(src + (size_t)r * DDIM);
  float4 v0 = row4[lane];
  float4 v1 = row4[lane + 64];
  uint2 p0, p1;
  p0.x = pk_bf16(v0.x, v0.y); p0.y = pk_bf16(v0.z, v0.w);
  p1.x = pk_bf16(v1.x, v1.y); p1.y = pk_bf16(v1.z, v1.w);
  *(uint2*)(dst16 + (size_t)r * DDIM + lane * 4) = p0;
  *(uint2*)(dst16 + (size_t)r * DDIM + 256 + lane * 4) = p1;
  float ss = v0.x*v0.x + v0.y*v0.y + v0.z*v0.z + v0.w*v0.w
           + v1.x*v1.x + v1.y*v1.y + v1.z*v1.z + v1.w*v1.w;
  #pragma unroll
  for (int off = 32; off; off >>= 1) ss += __shfl_down(ss, off);
  if (lane == 0) outv[r] = mode ? 2.0f / fmaxf(sqrtf(ss), 1e-12f) : ss;
}

// ---------- main MFMA pass: A-resident LDS, B L2->regs, depth-2 pipeline ----------
// 256 blocks (1/CU), 512 threads (8 waves = 2 row-halves x 4 code-quarters).
// A (128x512 bf16, 128 KiB) staged once into LDS (XOR-swizzled). B fragments
// load directly from the L2-resident bf16 codebook into registers with a
// DEPTH-2 rotation (aA/aB, bA/bB alternating, use-then-reload): the MFMAs of
// step s consume registers loaded at step s-2, giving ~2 full steps (600+cyc)
// of latency cover -- round 4's copy-based depth-1 only covered ~1 MFMA phase
// and stalled every step (MfmaUtil 21%, all pipes <25%). One raw s_barrier
// per 256-code tile paces all blocks onto the same codebook window (keeps B
// L2-resident: FETCH 33 MB in r2/r4 vs 805 MB unpaced r3).
// Register budget: frags 64 + acc 64(AGPR) + top2 48 + misc => ~230 unified,
// fits the 2-waves/SIMD budget (256). r5 showed 4 waves/SIMD forces spills.
__global__ __launch_bounds__(512, 2) void vq_mfma(const short* __restrict__ xb,
                                                  const short* __restrict__ eb,
                                                  const float* __restrict__ esq,
                                                  const float* __restrict__ inv2,
                                                  float* __restrict__ out_ind,
                                                  int* __restrict__ flags,
                                                  int* __restrict__ list,
                                                  int* __restrict__ cnt) {
  __shared__ __attribute__((aligned(16))) short As[128 * 512];   // 131072 B
  __shared__ float rS1[4][128];
  __shared__ float rS2[4][128];
  __shared__ int   rI1[4][128];

  const int tid = threadIdx.x;
  const int lane = tid & 63;
  const int w = tid >> 6;          // 0..7
  const int wr = w >> 2;           // row half (0..1): rows wr*64..+64
  const int wc = w & 3;            // code quarter within each 256-code tile
  const int q = lane >> 4, c16 = lane & 15;
  const int n0 = blockIdx.x * 128;

  // ---- A stage (once): LDS row j*8+w; physical 16B-chunk `lane` holds global
  // chunk lane^w (per-row XOR swizzle: logical chunk c at physical c ^ (row&7))
  #pragma unroll
  for (int j = 0; j < 16; ++j)
    async16(As + (j * 8 + w) * 512,
            xb + (size_t)(n0 + j * 8 + w) * 512 + (lane ^ w) * 8);

  const int arow0 = (wr * 64 + c16) * 512;   // + ti*8192 + ach (shorts)
  const int axor = (c16 & 7);

  // B global fragment base: code (col) = wc*64 + c16, k-chunk = q (8 dims, 16B).
  // Full addr adds ct*256*512 + tj*16*512 + s*32 (shorts).
  const short* gB = eb + (size_t)(wc * 64 + c16) * DDIM + q * 8;

  // inv2 values for my 16 row-slots (regs for whole kernel)
  f32x4 iv4[4];
  #pragma unroll
  for (int ti = 0; ti < 4; ++ti)
    iv4[ti] = *(const f32x4*)&inv2[n0 + wr * 64 + ti * 16 + q * 4];

  float s1[16], s2v[16];
  int   i1[16];
  #pragma unroll
  for (int s = 0; s < 16; ++s) { s1[s] = -3e38f; s2v[s] = -3e38f; i1[s] = 0; }

  // ---- depth-2 pipeline registers ----
  bf16x8 aA[4], aB[4], bA[4], bB[4];

  // B prologue (global, independent of LDS): g=0 -> bA, g=1 -> bB
  #pragma unroll
  for (int tj = 0; tj < 4; ++tj) {
    bA[tj] = *(const bf16x8*)(gB + (size_t)tj * 16 * DDIM);
    bB[tj] = *(const bf16x8*)(gB + (size_t)tj * 16 * DDIM + 32);
  }

  __syncthreads();   // A landed (the only full drain in the kernel)

  // A prologue: s=0 -> aA, s=1 -> aB
  #pragma unroll
  for (int ti = 0; ti < 4; ++ti) {
    aA[ti] = *(const bf16x8*)(As + arow0 + ti * 8192 + (((0 * 4 + q) ^ axor) * 8));
    aB[ti] = *(const bf16x8*)(As + arow0 + ti * 8192 + (((1 * 4 + q) ^ axor) * 8));
  }

  for (int ct = 0; ct < 16; ++ct) {
    const short* gBc = gB + (size_t)ct * 256 * DDIM;
    const short* gBc_next = (ct < 15) ? gBc + 256 * DDIM : gBc;  // clamp at end
    float nes[4];
    #pragma unroll
    for (int tj = 0; tj < 4; ++tj)
      nes[tj] = -esq[ct * 256 + wc * 64 + tj * 16 + c16];
    f32x4 acc[4][4];
    #pragma unroll
    for (int ti = 0; ti < 4; ++ti)
      #pragma unroll
      for (int tj = 0; tj < 4; ++tj) acc[ti][tj] = (f32x4){0.f, 0.f, 0.f, 0.f};

    #pragma unroll
    for (int s = 0; s < 16; s += 2) {
      // ---- even step s: consume aA/bA, then reload them for step s+2 ----
      __builtin_amdgcn_s_setprio(1);
      #pragma unroll
      for (int ti = 0; ti < 4; ++ti)
        #pragma unroll
        for (int tj = 0; tj < 4; ++tj)
          acc[ti][tj] = __builtin_amdgcn_mfma_f32_16x16x32_bf16(aA[ti], bA[tj], acc[ti][tj], 0, 0, 0);
      __builtin_amdgcn_s_setprio(0);
      {
        const int sn = (s + 2) & 15;                 // A pattern repeats every ct
        const int ach = ((sn * 4 + q) ^ axor) * 8;
        #pragma unroll
        for (int ti = 0; ti < 4; ++ti)
          aA[ti] = *(const bf16x8*)(As + arow0 + ti * 8192 + ach);
        const short* gBn = (s + 2 < 16) ? (gBc + (s + 2) * 32)
                                        : (gBc_next + (s + 2 - 16) * 32);
        #pragma unroll
        for (int tj = 0; tj < 4; ++tj)
          bA[tj] = *(const bf16x8*)(gBn + (size_t)tj * 16 * DDIM);
      }
      // ---- odd step s+1: consume aB/bB, then reload them for step s+3 ----
      __builtin_amdgcn_s_setprio(1);
      #pragma unroll
      for (int ti = 0; ti < 4; ++ti)
        #pragma unroll
        for (int tj = 0; tj < 4; ++tj)
          acc[ti][tj] = __builtin_amdgcn_mfma_f32_16x16x32_bf16(aB[ti], bB[tj], acc[ti][tj], 0, 0, 0);
      __builtin_amdgcn_s_setprio(0);
      {
        const int sn = (s + 3) & 15;
        const int ach = ((sn * 4 + q) ^ axor) * 8;
        #pragma unroll
        for (int ti = 0; ti < 4; ++ti)
          aB[ti] = *(const bf16x8*)(As + arow0 + ti * 8192 + ach);
        const short* gBn = (s + 3 < 16) ? (gBc + (s + 3) * 32)
                                        : (gBc_next + (s + 3 - 16) * 32);
        #pragma unroll
        for (int tj = 0; tj < 4; ++tj)
          bB[tj] = *(const bf16x8*)(gBn + (size_t)tj * 16 * DDIM);
      }
    }

    // ---------- epilogue for this 256-code tile (registers only) ----------
    // (also covers the latency of the already-issued next-ct prefetches)
    const int colbase = ct * 256 + wc * 64 + c16;
    #pragma unroll
    for (int ti = 0; ti < 4; ++ti)
      #pragma unroll
      for (int r = 0; r < 4; ++r) {
        const int slot = ti * 4 + r;
        const float iv = iv4[ti][r];
        #pragma unroll
        for (int tj = 0; tj < 4; ++tj) {
          float sc = fmaf(acc[ti][tj][r], iv, nes[tj]);
          float mn = fminf(sc, s1[slot]);
          s2v[slot] = fmaxf(s2v[slot], mn);
          if (sc > s1[slot]) { s1[slot] = sc; i1[slot] = colbase + tj * 16; }
        }
      }

    // pacing barrier: raw s_barrier, NO waitcnt drain (A read-only, B in regs).
    // Keeps all waves/blocks on the same codebook window -> L2-resident B.
    __builtin_amdgcn_s_barrier();
  }

  // ---------- final merge: 16 lanes -> 4 wc-waves -> write results ----------
  #pragma unroll
  for (int slot = 0; slot < 16; ++slot) {
    float a1 = s1[slot], a2 = s2v[slot]; int ai = i1[slot];
    #pragma unroll
    for (int off = 1; off < 16; off <<= 1) {
      float b1 = __shfl_xor(a1, off);
      float b2 = __shfl_xor(a2, off);
      int   bi = __shfl_xor(ai, off);
      float mn = fminf(a1, b1);
      a2 = fmaxf(fmaxf(a2, b2), mn);
      if (b1 > a1 || (b1 == a1 && bi < ai)) { a1 = b1; ai = bi; }
    }
    if (c16 == 0) {
      int row = wr * 64 + (slot >> 2) * 16 + q * 4 + (slot & 3);
      rS1[wc][row] = a1; rS2[wc][row] = a2; rI1[wc][row] = ai;
    }
  }
  __syncthreads();
  if (tid < 128) {
    float a1 = rS1[0][tid], a2 = rS2[0][tid]; int ai = rI1[0][tid];
    #pragma unroll
    for (int gq = 1; gq < 4; ++gq) {
      float b1 = rS1[gq][tid], b2 = rS2[gq][tid]; int bi = rI1[gq][tid];
      float mn = fminf(a1, b1);
      a2 = fmaxf(fmaxf(a2, b2), mn);
      if (b1 > a1 || (b1 == a1 && bi < ai)) { a1 = b1; ai = bi; }
    }
    const int row = n0 + tid;
    out_ind[row] = (float)ai;
    if (a1 - a2 < EPS) {
      int p = atomicAdd(cnt, 1);
      list[p] = row;
      flags[row] = p + 1;
    } else {
      flags[row] = 0;
    }
  }
}

// ---------- cleanup: exact fp32 rescore of flagged rows (split 8 k-chunks) ----------
__global__ __launch_bounds__(256) void cleanup_kernel(const float* __restrict__ x,
                                                      const float* __restrict__ embed,
                                                      const float* __restrict__ esq,
                                                      const float* __restrict__ inv2,
                                                      const int* __restrict__ list,
                                                      const int* __restrict__ cnt,
                                                      float2* __restrict__ exact) {
  __shared__ float xr[DDIM];
  __shared__ float red_s[4];
  __shared__ int   red_i[4];
  const int rs = blockIdx.x & 31, kc = blockIdx.x >> 5;
  const int tid = threadIdx.x;
  const int lane = tid & 63, wid = tid >> 6;
  const int n = *cnt;
  for (int ii = rs; ii < n; ii += 32) {
    const int row = list[ii];
    __syncthreads();
    if (tid < 128) *(float4*)&xr[tid * 4] = *(const float4*)&x[(size_t)row * DDIM + tid * 4];
    __syncthreads();
    const float iv = inv2[row];
    float bs = -3e38f; int bi = 0;
    for (int cc = 0; cc < 2; ++cc) {
      const int code = kc * 512 + cc * 256 + tid;
      const float4* er = (const float4*)&embed[(size_t)code * DDIM];
      float acc = 0.f;
      for (int d = 0; d < DDIM / 4; ++d) {
        float4 e4 = er[d];
        float4 x4 = *(const float4*)&xr[d * 4];
        acc += x4.x * e4.x + x4.y * e4.y + x4.z * e4.z + x4.w * e4.w;
      }
      float sc = fmaf(acc, iv, -esq[code]);
      if (sc > bs || (sc == bs && code < bi)) { bs = sc; bi = code; }
    }
    #pragma unroll
    for (int off = 1; off < 64; off <<= 1) {
      float b1 = __shfl_xor(bs, off);
      int   b2 = __shfl_xor(bi, off);
      if (b1 > bs || (b1 == bs && b2 < bi)) { bs = b1; bi = b2; }
    }
    if (lane == 0) { red_s[wid] = bs; red_i[wid] = bi; }
    __syncthreads();
    if (tid == 0) {
      for (int ww = 1; ww < 4; ++ww)
        if (red_s[ww] > red_s[0] || (red_s[ww] == red_s[0] && red_i[ww] < red_i[0])) {
          red_s[0] = red_s[ww]; red_i[0] = red_i[ww];
        }
      exact[(size_t)ii * 8 + kc] = make_float2(red_s[0], (float)red_i[0]);
    }
  }
}

// ---------- gather + transpose (merges exact results for flagged rows) ----------
__global__ __launch_bounds__(256) void gather_kernel(const float* __restrict__ embed,
                                                     const int* __restrict__ flags,
                                                     const float2* __restrict__ exact,
                                                     float* __restrict__ out_ind,
                                                     float* __restrict__ out_q) {
  __shared__ int lidx[64];
  __shared__ float trans[64 * 65];
  const int n0 = blockIdx.x * 64;
  const int tid = threadIdx.x;
  if (tid < 64) {
    const int row = n0 + tid;
    const int f = flags[row];
    int idx;
    if (f) {
      float bsv = -3e38f; int bi = 0;
      const float2* e8 = &exact[(size_t)(f - 1) * 8];
      #pragma unroll
      for (int k = 0; k < 8; ++k) {
        float2 t = e8[k];
        int ci = (int)t.y;
        if (t.x > bsv || (t.x == bsv && ci < bi)) { bsv = t.x; bi = ci; }
      }
      idx = bi;
      out_ind[row] = (float)idx;
    } else {
      idx = (int)out_ind[row];
    }
    lidx[tid] = idx;
  }
  __syncthreads();
  const int bb = n0 >> 12;
  const int t0 = n0 & (TT - 1);
  const int w = tid >> 6, lane = tid & 63;
  for (int d0 = 0; d0 < DDIM; d0 += 64) {
    if (d0) __syncthreads();
    #pragma unroll
    for (int qq = 0; qq < 16; ++qq) {
      int tt2 = w * 16 + qq;
      int e = lidx[tt2];
      trans[lane * 65 + tt2] = embed[(size_t)e * DDIM + d0 + lane];
    }
    __syncthreads();
    #pragma unroll
    for (int qq = 0; qq < 4; ++qq) {
      int dl = (tid >> 4) * 4 + qq;
      int t4 = (tid & 15) * 4;
      float4 o;
      o.x = trans[dl * 65 + t4 + 0];
      o.y = trans[dl * 65 + t4 + 1];
      o.z = trans[dl * 65 + t4 + 2];
      o.w = trans[dl * 65 + t4 + 3];
      *(float4*)&out_q[((size_t)bb * DDIM + d0 + dl) * TT + t0 + t4] = o;
    }
  }
}

extern "C" void kernel_launch(void* const* d_in, const int* in_sizes, int n_in,
                              void* d_out, int out_size, void* d_ws, size_t ws_size,
                              hipStream_t stream) {
  const float* x     = (const float*)d_in[0];
  const float* embed = (const float*)d_in[1];
  char* ws = (char*)d_ws;
  short* xb      = (short*)(ws);                         // 33,554,432 B
  short* eb      = (short*)(ws + 33554432);              //  4,194,304 B
  float* esq     = (float*)(ws + 37748736);              //     16,384 B
  float* inv2    = (float*)(ws + 37765120);              //    131,072 B
  int* list      = (int*)(ws + 39993344);                //    131,072 B
  int* flags     = (int*)(ws + 40124416);                //    131,072 B
  float2* exact  = (float2*)(ws + 40255488);             //  2,097,152 B
  int* cnt       = (int*)(ws + 42352640);                //          4 B

  float* out_ind = (float*)d_out;
  float* out_q   = out_ind + NN;

  prep_kernel<<<KK / 4, 256, 0, stream>>>(embed, eb, esq, 0);
  prep_kernel<<<NN / 4, 256, 0, stream>>>(x, xb, inv2, 1);
  hipMemsetAsync(cnt, 0, 4, stream);
  vq_mfma<<<256, 512, 0, stream>>>(xb, eb, esq, inv2, out_ind, flags, list, cnt);
  cleanup_kernel<<<256, 256, 0, stream>>>(x, embed, esq, inv2, list, cnt, exact);
  gather_kernel<<<NN / 64, 256, 0, stream>>>(embed, flags, exact, out_ind, out_q);
}

// Round 8
// 321.924 us; speedup vs baseline: 1.7008x; 1.2768x over previous
//
#include <hip/hip_runtime.h>
#include <math.h>

#define BB 8
#define TT 4096
#define DDIM 512
#define KK 4096
#define NN (BB*TT)
#define EPS 0.05f

typedef __attribute__((ext_vector_type(8))) short bf16x8;
typedef __attribute__((ext_vector_type(4))) float f32x4;

__device__ __forceinline__ void async16(void* lds, const void* g) {
  __builtin_amdgcn_global_load_lds((const __attribute__((address_space(1))) void*)g,
                                   (__attribute__((address_space(3))) void*)lds, 16, 0, 0);
}

__device__ __forceinline__ unsigned pk_bf16(float a, float b) {
  unsigned ua = __float_as_uint(a); ua += 0x7FFFu + ((ua >> 16) & 1u);
  unsigned ub = __float_as_uint(b); ub += 0x7FFFu + ((ub >> 16) & 1u);
  return (ua >> 16) | (ub & 0xFFFF0000u);
}

// ---------- prep: row sum-sq (esq or inv2=2/norm) + bf16 (RTNE) conversion ----------
__global__ __launch_bounds__(256) void prep_kernel(const float* __restrict__ src,
                                                   short* __restrict__ dst16,
                                                   float* __restrict__ outv, int mode) {
  int r = blockIdx.x * 4 + (threadIdx.x >> 6);
  int lane = threadIdx.x & 63;
  const float4* row4 = (const float4*)(src + (size_t)r * DDIM);
  float4 v0 = row4[lane];
  float4 v1 = row4[lane + 64];
  uint2 p0, p1;
  p0.x = pk_bf16(v0.x, v0.y); p0.y = pk_bf16(v0.z, v0.w);
  p1.x = pk_bf16(v1.x, v1.y); p1.y = pk_bf16(v1.z, v1.w);
  *(uint2*)(dst16 + (size_t)r * DDIM + lane * 4) = p0;
  *(uint2*)(dst16 + (size_t)r * DDIM + 256 + lane * 4) = p1;
  float ss = v0.x*v0.x + v0.y*v0.y + v0.z*v0.z + v0.w*v0.w
           + v1.x*v1.x + v1.y*v1.y + v1.z*v1.z + v1.w*v1.w;
  #pragma unroll
  for (int off = 32; off; off >>= 1) ss += __shfl_down(ss, off);
  if (lane == 0) outv[r] = mode ? 2.0f / fmaxf(sqrtf(ss), 1e-12f) : ss;
}

// ---------- main MFMA pass: r2 structure + counted-vmcnt sync (T3/T4) ----------
// 256 blocks (1/CU), 512 threads (8 waves = 2 row-halves x 4 code-quarters).
// A (128 rows x 512 dims bf16, 128 KiB) staged ONCE into LDS; codebook streams
// through a 2 x 16 KiB LDS double buffer via global_load_lds (async DMA).
// IDENTICAL data path to round 2 (195 us, absmax=0) -- only the sync skeleton
// changes: round 2's per-step __syncthreads (= s_waitcnt vmcnt(0) lgkmcnt(0)
// drain, ~700 cyc/step serial) is replaced by:
//   ds_read+MFMA ; s_barrier(A) ; STAGE(g+2)->freed buf ; vmcnt(2) ; s_barrier(B)
// so the next chunk's 2 DMA loads stay IN FLIGHT across both barriers (vmcnt
// never drains to 0 until the tail). Correctness: barrier A proves all waves
// consumed buf g&1 (MFMA uses force lgkm waits) before its DMA overwrite;
// vmcnt(2) (all-but-newest-2 complete) + barrier B prove STAGE(g+1) landed
// block-wide before any wave reads it. Compiler-placed esq/inv2 loads are
// FIFO-older than the newest stage pair => vmcnt(2) stays conservative-safe.
__global__ __launch_bounds__(512, 2) void vq_mfma(const short* __restrict__ xb,
                                                  const short* __restrict__ eb,
                                                  const float* __restrict__ esq,
                                                  const float* __restrict__ inv2,
                                                  float* __restrict__ out_ind,
                                                  int* __restrict__ flags,
                                                  int* __restrict__ list,
                                                  int* __restrict__ cnt) {
  __shared__ __attribute__((aligned(16))) short As[128 * 512];    // 131072 B
  __shared__ __attribute__((aligned(16))) short Bs[2 * 256 * 32]; //  32768 B

  const int tid = threadIdx.x;
  const int lane = tid & 63;
  const int w = tid >> 6;          // 0..7
  const int wr = w >> 2;           // row half (0..1): rows wr*64..+64
  const int wc = w & 3;            // code quarter within 256-tile
  const int q = lane >> 4, c16 = lane & 15;
  const int n0 = blockIdx.x * 128;

  // ---- A stage (once): LDS row j*8+w; phys 16B-chunk `lane` holds global chunk lane^w
  #pragma unroll
  for (int j = 0; j < 16; ++j)
    async16(As + (j * 8 + w) * 512,
            xb + (size_t)(n0 + j * 8 + w) * 512 + (lane ^ w) * 8);

  // ---- B stage thread constants (pair-window swizzle, as r2) ----
  const int x = (lane & 7) ^ (lane >> 3);
  const int scode = w * 16 + (lane >> 3) * 2 + (x >> 2);   // k=0 local code
  const short* gB = eb + (size_t)scode * 512 + (x & 3) * 8;
  short* sB0 = Bs + w * 512;                                // + buf*8192

  // stage chunk gn (0..255) into buf gn&1
#define STAGE(gn) do {                                                     \
    const short* src_ = gB + (size_t)((gn) >> 4) * (256 * 512) + ((gn) & 15) * 32; \
    short* dst_ = Bs + (((gn) & 1) << 13) + w * 512;                       \
    async16(dst_,        src_);                                            \
    async16(dst_ + 4096, src_ + 128 * 512); } while (0)

  STAGE(0);
  STAGE(1);

  // ---- fragment read constants ----
  const int sigB8 = ((((c16 & 1) << 2) | q) ^ ((c16 >> 1) & 7)) * 8;
  const int brow0 = (wc * 32 + (c16 >> 1)) * 64 + sigB8;    // + tj*512 + buf*8192
  const int arow0 = (wr * 64 + c16) * 512;                  // + ti*8192 + ach

  // inv2 values for my 16 row-slots (regs for whole kernel)
  f32x4 iv4[4];
  #pragma unroll
  for (int ti = 0; ti < 4; ++ti)
    iv4[ti] = *(const f32x4*)&inv2[n0 + wr * 64 + ti * 16 + q * 4];

  float s1[16], s2v[16];
  int   i1[16];
  #pragma unroll
  for (int s = 0; s < 16; ++s) { s1[s] = -3e38f; s2v[s] = -3e38f; i1[s] = 0; }

  // prologue wait: A (16 loads) + STAGE(0) landed for me; STAGE(1) in flight.
  asm volatile("s_waitcnt vmcnt(2)" ::: "memory");
  asm volatile("s_barrier" ::: "memory");   // all waves' A + STAGE(0) landed

  for (int ct = 0; ct < 16; ++ct) {
    float nes[4];
    #pragma unroll
    for (int tj = 0; tj < 4; ++tj)
      nes[tj] = -esq[ct * 256 + wc * 64 + tj * 16 + c16];
    f32x4 acc[4][4];
    #pragma unroll
    for (int ti = 0; ti < 4; ++ti)
      #pragma unroll
      for (int tj = 0; tj < 4; ++tj) acc[ti][tj] = (f32x4){0.f, 0.f, 0.f, 0.f};

    #pragma unroll 2
    for (int s = 0; s < 16; ++s) {
      const int g = ct * 16 + s;
      // ---- compute on buf g&1 (staged by STAGE(g), proven landed by barrier B of step g-1)
      const short* Ap = As + arow0;
      const short* Bp = Bs + ((g & 1) << 13) + brow0;
      const int ach = ((s * 4 + q) ^ (c16 & 7)) * 8;
      bf16x8 af[4], bf[4];
      #pragma unroll
      for (int ti = 0; ti < 4; ++ti)
        af[ti] = *(const bf16x8*)(Ap + ti * 8192 + ach);
      #pragma unroll
      for (int tj = 0; tj < 4; ++tj)
        bf[tj] = *(const bf16x8*)(Bp + tj * 512);
      __builtin_amdgcn_s_setprio(1);
      #pragma unroll
      for (int ti = 0; ti < 4; ++ti)
        #pragma unroll
        for (int tj = 0; tj < 4; ++tj)
          acc[ti][tj] = __builtin_amdgcn_mfma_f32_16x16x32_bf16(af[ti], bf[tj], acc[ti][tj], 0, 0, 0);
      __builtin_amdgcn_s_setprio(0);
      // barrier A: every wave has consumed buf g&1 (lgkm forced by MFMA uses)
      asm volatile("s_barrier" ::: "memory");
      if (g <= 253) {
        STAGE(g + 2);   // overwrite buf g&1 -- safe after barrier A
        // counted wait: all but the newest 2 loads (= STAGE(g+2)) complete
        // => STAGE(g+1) landed. Never drains the queue.
        asm volatile("s_waitcnt vmcnt(2)" ::: "memory");
      } else if (g == 254) {
        asm volatile("s_waitcnt vmcnt(0)" ::: "memory");  // tail: STAGE(255) landed
      }
      // barrier B: STAGE(g+1) landed block-wide -> buf (g+1)&1 readable
      asm volatile("s_barrier" ::: "memory");
    }

    // ---------- epilogue for this 256-code tile (registers only) ----------
    const int colbase = ct * 256 + wc * 64 + c16;
    #pragma unroll
    for (int ti = 0; ti < 4; ++ti)
      #pragma unroll
      for (int r = 0; r < 4; ++r) {
        const int slot = ti * 4 + r;
        const float iv = iv4[ti][r];
        #pragma unroll
        for (int tj = 0; tj < 4; ++tj) {
          float sc = fmaf(acc[ti][tj][r], iv, nes[tj]);
          float mn = fminf(sc, s1[slot]);
          s2v[slot] = fmaxf(s2v[slot], mn);
          if (sc > s1[slot]) { s1[slot] = sc; i1[slot] = colbase + tj * 16; }
        }
      }
  }
#undef STAGE

  // ---------- final merge: 16 lanes -> 4 wc-waves -> write results ----------
  __syncthreads();   // full drain; Bs reusable below
  float* rS1 = (float*)Bs;           // [4][128]
  float* rS2 = rS1 + 512;
  int*   rI1 = (int*)(rS2 + 512);
  #pragma unroll
  for (int slot = 0; slot < 16; ++slot) {
    float a1 = s1[slot], a2 = s2v[slot]; int ai = i1[slot];
    #pragma unroll
    for (int off = 1; off < 16; off <<= 1) {
      float b1 = __shfl_xor(a1, off);
      float b2 = __shfl_xor(a2, off);
      int   bi = __shfl_xor(ai, off);
      float mn = fminf(a1, b1);
      a2 = fmaxf(fmaxf(a2, b2), mn);
      if (b1 > a1 || (b1 == a1 && bi < ai)) { a1 = b1; ai = bi; }
    }
    if (c16 == 0) {
      int row = wr * 64 + (slot >> 2) * 16 + q * 4 + (slot & 3);
      rS1[wc * 128 + row] = a1; rS2[wc * 128 + row] = a2; rI1[wc * 128 + row] = ai;
    }
  }
  __syncthreads();
  if (tid < 128) {
    float a1 = rS1[tid], a2 = rS2[tid]; int ai = rI1[tid];
    #pragma unroll
    for (int gq = 1; gq < 4; ++gq) {
      float b1 = rS1[gq * 128 + tid], b2 = rS2[gq * 128 + tid]; int bi = rI1[gq * 128 + tid];
      float mn = fminf(a1, b1);
      a2 = fmaxf(fmaxf(a2, b2), mn);
      if (b1 > a1 || (b1 == a1 && bi < ai)) { a1 = b1; ai = bi; }
    }
    const int row = n0 + tid;
    out_ind[row] = (float)ai;
    if (a1 - a2 < EPS) {
      int p = atomicAdd(cnt, 1);
      list[p] = row;
      flags[row] = p + 1;
    } else {
      flags[row] = 0;
    }
  }
}

// ---------- cleanup: exact fp32 rescore of flagged rows (split 8 k-chunks) ----------
__global__ __launch_bounds__(256) void cleanup_kernel(const float* __restrict__ x,
                                                      const float* __restrict__ embed,
                                                      const float* __restrict__ esq,
                                                      const float* __restrict__ inv2,
                                                      const int* __restrict__ list,
                                                      const int* __restrict__ cnt,
                                                      float2* __restrict__ exact) {
  __shared__ float xr[DDIM];
  __shared__ float red_s[4];
  __shared__ int   red_i[4];
  const int rs = blockIdx.x & 31, kc = blockIdx.x >> 5;
  const int tid = threadIdx.x;
  const int lane = tid & 63, wid = tid >> 6;
  const int n = *cnt;
  for (int ii = rs; ii < n; ii += 32) {
    const int row = list[ii];
    __syncthreads();
    if (tid < 128) *(float4*)&xr[tid * 4] = *(const float4*)&x[(size_t)row * DDIM + tid * 4];
    __syncthreads();
    const float iv = inv2[row];
    float bs = -3e38f; int bi = 0;
    for (int cc = 0; cc < 2; ++cc) {
      const int code = kc * 512 + cc * 256 + tid;
      const float4* er = (const float4*)&embed[(size_t)code * DDIM];
      float acc = 0.f;
      for (int d = 0; d < DDIM / 4; ++d) {
        float4 e4 = er[d];
        float4 x4 = *(const float4*)&xr[d * 4];
        acc += x4.x * e4.x + x4.y * e4.y + x4.z * e4.z + x4.w * e4.w;
      }
      float sc = fmaf(acc, iv, -esq[code]);
      if (sc > bs || (sc == bs && code < bi)) { bs = sc; bi = code; }
    }
    #pragma unroll
    for (int off = 1; off < 64; off <<= 1) {
      float b1 = __shfl_xor(bs, off);
      int   b2 = __shfl_xor(bi, off);
      if (b1 > bs || (b1 == bs && b2 < bi)) { bs = b1; bi = b2; }
    }
    if (lane == 0) { red_s[wid] = bs; red_i[wid] = bi; }
    __syncthreads();
    if (tid == 0) {
      for (int ww = 1; ww < 4; ++ww)
        if (red_s[ww] > red_s[0] || (red_s[ww] == red_s[0] && red_i[ww] < red_i[0])) {
          red_s[0] = red_s[ww]; red_i[0] = red_i[ww];
        }
      exact[(size_t)ii * 8 + kc] = make_float2(red_s[0], (float)red_i[0]);
    }
  }
}

// ---------- gather + transpose (merges exact results for flagged rows) ----------
__global__ __launch_bounds__(256) void gather_kernel(const float* __restrict__ embed,
                                                     const int* __restrict__ flags,
                                                     const float2* __restrict__ exact,
                                                     float* __restrict__ out_ind,
                                                     float* __restrict__ out_q) {
  __shared__ int lidx[64];
  __shared__ float trans[64 * 65];
  const int n0 = blockIdx.x * 64;
  const int tid = threadIdx.x;
  if (tid < 64) {
    const int row = n0 + tid;
    const int f = flags[row];
    int idx;
    if (f) {
      float bsv = -3e38f; int bi = 0;
      const float2* e8 = &exact[(size_t)(f - 1) * 8];
      #pragma unroll
      for (int k = 0; k < 8; ++k) {
        float2 t = e8[k];
        int ci = (int)t.y;
        if (t.x > bsv || (t.x == bsv && ci < bi)) { bsv = t.x; bi = ci; }
      }
      idx = bi;
      out_ind[row] = (float)idx;
    } else {
      idx = (int)out_ind[row];
    }
    lidx[tid] = idx;
  }
  __syncthreads();
  const int bb = n0 >> 12;
  const int t0 = n0 & (TT - 1);
  const int w = tid >> 6, lane = tid & 63;
  for (int d0 = 0; d0 < DDIM; d0 += 64) {
    if (d0) __syncthreads();
    #pragma unroll
    for (int qq = 0; qq < 16; ++qq) {
      int tt2 = w * 16 + qq;
      int e = lidx[tt2];
      trans[lane * 65 + tt2] = embed[(size_t)e * DDIM + d0 + lane];
    }
    __syncthreads();
    #pragma unroll
    for (int qq = 0; qq < 4; ++qq) {
      int dl = (tid >> 4) * 4 + qq;
      int t4 = (tid & 15) * 4;
      float4 o;
      o.x = trans[dl * 65 + t4 + 0];
      o.y = trans[dl * 65 + t4 + 1];
      o.z = trans[dl * 65 + t4 + 2];
      o.w = trans[dl * 65 + t4 + 3];
      *(float4*)&out_q[((size_t)bb * DDIM + d0 + dl) * TT + t0 + t4] = o;
    }
  }
}

extern "C" void kernel_launch(void* const* d_in, const int* in_sizes, int n_in,
                              void* d_out, int out_size, void* d_ws, size_t ws_size,
                              hipStream_t stream) {
  const float* x     = (const float*)d_in[0];
  const float* embed = (const float*)d_in[1];
  char* ws = (char*)d_ws;
  short* xb      = (short*)(ws);                         // 33,554,432 B
  short* eb      = (short*)(ws + 33554432);              //  4,194,304 B
  float* esq     = (float*)(ws + 37748736);              //     16,384 B
  float* inv2    = (float*)(ws + 37765120);              //    131,072 B
  int* list      = (int*)(ws + 39993344);                //    131,072 B
  int* flags     = (int*)(ws + 40124416);                //    131,072 B
  float2* exact  = (float2*)(ws + 40255488);             //  2,097,152 B
  int* cnt       = (int*)(ws + 42352640);                //          4 B

  float* out_ind = (float*)d_out;
  float* out_q   = out_ind + NN;

  prep_kernel<<<KK / 4, 256, 0, stream>>>(embed, eb, esq, 0);
  prep_kernel<<<NN / 4, 256, 0, stream>>>(x, xb, inv2, 1);
  hipMemsetAsync(cnt, 0, 4, stream);
  vq_mfma<<<256, 512, 0, stream>>>(xb, eb, esq, inv2, out_ind, flags, list, cnt);
  cleanup_kernel<<<256, 256, 0, stream>>>(x, embed, esq, inv2, list, cnt, exact);
  gather_kernel<<<NN / 64, 256, 0, stream>>>(embed, flags, exact, out_ind, out_q);
}

// Round 9
// 315.207 us; speedup vs baseline: 1.7371x; 1.0213x over previous
//
#include <hip/hip_runtime.h>
#include <math.h>

#define BB 8
#define TT 4096
#define DDIM 512
#define KK 4096
#define NN (BB*TT)
#define EPS 0.05f

typedef __attribute__((ext_vector_type(8))) short bf16x8;
typedef __attribute__((ext_vector_type(4))) float f32x4;

__device__ __forceinline__ void async16(void* lds, const void* g) {
  __builtin_amdgcn_global_load_lds((const __attribute__((address_space(1))) void*)g,
                                   (__attribute__((address_space(3))) void*)lds, 16, 0, 0);
}

__device__ __forceinline__ unsigned pk_bf16(float a, float b) {
  unsigned ua = __float_as_uint(a); ua += 0x7FFFu + ((ua >> 16) & 1u);
  unsigned ub = __float_as_uint(b); ub += 0x7FFFu + ((ub >> 16) & 1u);
  return (ua >> 16) | (ub & 0xFFFF0000u);
}

// ---------- prep (embed only now): row sum-sq + bf16 (RTNE) conversion ----------
__global__ __launch_bounds__(256) void prep_kernel(const float* __restrict__ src,
                                                   short* __restrict__ dst16,
                                                   float* __restrict__ outv, int mode) {
  int r = blockIdx.x * 4 + (threadIdx.x >> 6);
  int lane = threadIdx.x & 63;
  const float4* row4 = (const float4*)(src + (size_t)r * DDIM);
  float4 v0 = row4[lane];
  float4 v1 = row4[lane + 64];
  uint2 p0, p1;
  p0.x = pk_bf16(v0.x, v0.y); p0.y = pk_bf16(v0.z, v0.w);
  p1.x = pk_bf16(v1.x, v1.y); p1.y = pk_bf16(v1.z, v1.w);
  *(uint2*)(dst16 + (size_t)r * DDIM + lane * 4) = p0;
  *(uint2*)(dst16 + (size_t)r * DDIM + 256 + lane * 4) = p1;
  float ss = v0.x*v0.x + v0.y*v0.y + v0.z*v0.z + v0.w*v0.w
           + v1.x*v1.x + v1.y*v1.y + v1.z*v1.z + v1.w*v1.w;
  #pragma unroll
  for (int off = 32; off; off >>= 1) ss += __shfl_down(ss, off);
  if (lane == 0) outv[r] = mode ? 2.0f / fmaxf(sqrtf(ss), 1e-12f) : ss;
}

// ---------- main MFMA pass: fused x-prep + r8 counted-vmcnt loop ----------
// 256 blocks (1/CU), 512 threads (8 waves = 2 row-halves x 4 code-quarters).
// FUSION (new vs r8): the block converts its own 128 rows of x (f32) to bf16
// in-LDS (same pk_bf16 + identical per-lane sum order + identical __shfl_down
// tree as the old prep => bit-identical inv2), writes A via ds_write with the
// SAME XOR-chunk swizzle the DMA produced (logical chunk c at physical
// c ^ (row&7)), parks inv2 in Bs (pre-STAGE) for the epilogue, and stores it
// to global for cleanup. Eliminates the prep_x kernel: -128 MB read -64 MB
// write +32 MB (f32 A vs bf16 A) = -160 MB HBM (~25 us).
// Main loop is byte-for-byte r8's proven skeleton (186.8 us, absmax=0):
//   ds_read+MFMA ; s_barrier ; STAGE(g+2) ; vmcnt(2) ; s_barrier
__global__ __launch_bounds__(512, 2) void vq_mfma(const float* __restrict__ xf,
                                                  const short* __restrict__ eb,
                                                  const float* __restrict__ esq,
                                                  float* __restrict__ inv2g,
                                                  float* __restrict__ out_ind,
                                                  int* __restrict__ flags,
                                                  int* __restrict__ list,
                                                  int* __restrict__ cnt) {
  __shared__ __attribute__((aligned(16))) short As[128 * 512];    // 131072 B
  __shared__ __attribute__((aligned(16))) short Bs[2 * 256 * 32]; //  32768 B

  const int tid = threadIdx.x;
  const int lane = tid & 63;
  const int w = tid >> 6;          // 0..7
  const int wr = w >> 2;           // row half (0..1): rows wr*64..+64
  const int wc = w & 3;            // code quarter within 256-tile
  const int q = lane >> 4, c16 = lane & 15;
  const int n0 = blockIdx.x * 128;

  // ---- fused A prep: wave w converts rows w*16 .. w*16+15 ----
  #pragma unroll 2
  for (int j = 0; j < 16; ++j) {
    const int rl = w * 16 + j;       // local row 0..127
    const float4* row4 = (const float4*)(xf + (size_t)(n0 + rl) * DDIM);
    float4 v0 = row4[lane];
    float4 v1 = row4[lane + 64];
    uint2 p0, p1;
    p0.x = pk_bf16(v0.x, v0.y); p0.y = pk_bf16(v0.z, v0.w);
    p1.x = pk_bf16(v1.x, v1.y); p1.y = pk_bf16(v1.z, v1.w);
    // ds_write with chunk swizzle: logical 16B-chunk c stored at c ^ (rl&7).
    // lane covers logical chunks (lane>>1) and 32+(lane>>1), half (lane&1).
    const int rx = rl & 7;
    char* rowbase = (char*)(As + rl * 512);
    *(uint2*)(rowbase + ((((lane >> 1)     ) ^ rx) * 16 + (lane & 1) * 8)) = p0;
    *(uint2*)(rowbase + ((((lane >> 1) + 32) ^ rx) * 16 + (lane & 1) * 8)) = p1;
    // identical summation + reduction order as old prep => bit-identical inv2
    float ss = v0.x*v0.x + v0.y*v0.y + v0.z*v0.z + v0.w*v0.w
             + v1.x*v1.x + v1.y*v1.y + v1.z*v1.z + v1.w*v1.w;
    #pragma unroll
    for (int off = 32; off; off >>= 1) ss += __shfl_down(ss, off);
    if (lane == 0) {
      float inv = 2.0f / fmaxf(sqrtf(ss), 1e-12f);
      ((float*)Bs)[rl] = inv;        // park for epilogue (pre-STAGE)
      inv2g[n0 + rl] = inv;          // for cleanup kernel
    }
  }
  __syncthreads();                   // A writes + parked inv2 visible

  // read my 16 row-slots' inv2 into regs, then Bs is free for staging
  f32x4 iv4[4];
  #pragma unroll
  for (int ti = 0; ti < 4; ++ti)
    iv4[ti] = *(const f32x4*)&((const float*)Bs)[wr * 64 + ti * 16 + q * 4];
  __syncthreads();                   // everyone has iv4; Bs reusable

  // ---- B stage thread constants (pair-window swizzle, as r2/r8) ----
  const int x = (lane & 7) ^ (lane >> 3);
  const int scode = w * 16 + (lane >> 3) * 2 + (x >> 2);   // k=0 local code
  const short* gB = eb + (size_t)scode * 512 + (x & 3) * 8;

  // stage chunk gn (0..255) into buf gn&1
#define STAGE(gn) do {                                                     \
    const short* src_ = gB + (size_t)((gn) >> 4) * (256 * 512) + ((gn) & 15) * 32; \
    short* dst_ = Bs + (((gn) & 1) << 13) + w * 512;                       \
    async16(dst_,        src_);                                            \
    async16(dst_ + 4096, src_ + 128 * 512); } while (0)

  STAGE(0);
  STAGE(1);

  // ---- fragment read constants ----
  const int sigB8 = ((((c16 & 1) << 2) | q) ^ ((c16 >> 1) & 7)) * 8;
  const int brow0 = (wc * 32 + (c16 >> 1)) * 64 + sigB8;    // + tj*512 + buf*8192
  const int arow0 = (wr * 64 + c16) * 512;                  // + ti*8192 + ach

  float s1[16], s2v[16];
  int   i1[16];
  #pragma unroll
  for (int s = 0; s < 16; ++s) { s1[s] = -3e38f; s2v[s] = -3e38f; i1[s] = 0; }

  // prologue wait: STAGE(0) landed (older inv2g stores also forced done);
  // STAGE(1) stays in flight.
  asm volatile("s_waitcnt vmcnt(2)" ::: "memory");
  asm volatile("s_barrier" ::: "memory");

  for (int ct = 0; ct < 16; ++ct) {
    float nes[4];
    #pragma unroll
    for (int tj = 0; tj < 4; ++tj)
      nes[tj] = -esq[ct * 256 + wc * 64 + tj * 16 + c16];
    f32x4 acc[4][4];
    #pragma unroll
    for (int ti = 0; ti < 4; ++ti)
      #pragma unroll
      for (int tj = 0; tj < 4; ++tj) acc[ti][tj] = (f32x4){0.f, 0.f, 0.f, 0.f};

    #pragma unroll 2
    for (int s = 0; s < 16; ++s) {
      const int g = ct * 16 + s;
      // ---- compute on buf g&1 (landed: barrier B of step g-1) ----
      const short* Ap = As + arow0;
      const short* Bp = Bs + ((g & 1) << 13) + brow0;
      const int ach = ((s * 4 + q) ^ (c16 & 7)) * 8;
      bf16x8 af[4], bf[4];
      #pragma unroll
      for (int ti = 0; ti < 4; ++ti)
        af[ti] = *(const bf16x8*)(Ap + ti * 8192 + ach);
      #pragma unroll
      for (int tj = 0; tj < 4; ++tj)
        bf[tj] = *(const bf16x8*)(Bp + tj * 512);
      __builtin_amdgcn_s_setprio(1);
      #pragma unroll
      for (int ti = 0; ti < 4; ++ti)
        #pragma unroll
        for (int tj = 0; tj < 4; ++tj)
          acc[ti][tj] = __builtin_amdgcn_mfma_f32_16x16x32_bf16(af[ti], bf[tj], acc[ti][tj], 0, 0, 0);
      __builtin_amdgcn_s_setprio(0);
      // barrier A: every wave has consumed buf g&1 (ds_reads done pre-MFMA)
      asm volatile("s_barrier" ::: "memory");
      if (g <= 253) {
        STAGE(g + 2);   // overwrite buf g&1 -- safe after barrier A
        asm volatile("s_waitcnt vmcnt(2)" ::: "memory");  // STAGE(g+1) landed
      } else if (g == 254) {
        asm volatile("s_waitcnt vmcnt(0)" ::: "memory");  // tail
      }
      // barrier B: STAGE(g+1) landed block-wide -> buf (g+1)&1 readable
      asm volatile("s_barrier" ::: "memory");
    }

    // ---------- epilogue for this 256-code tile (registers only) ----------
    const int colbase = ct * 256 + wc * 64 + c16;
    #pragma unroll
    for (int ti = 0; ti < 4; ++ti)
      #pragma unroll
      for (int r = 0; r < 4; ++r) {
        const int slot = ti * 4 + r;
        const float iv = iv4[ti][r];
        #pragma unroll
        for (int tj = 0; tj < 4; ++tj) {
          float sc = fmaf(acc[ti][tj][r], iv, nes[tj]);
          float mn = fminf(sc, s1[slot]);
          s2v[slot] = fmaxf(s2v[slot], mn);
          if (sc > s1[slot]) { s1[slot] = sc; i1[slot] = colbase + tj * 16; }
        }
      }
  }
#undef STAGE

  // ---------- final merge: 16 lanes -> 4 wc-waves -> write results ----------
  __syncthreads();   // full drain; Bs reusable below
  float* rS1 = (float*)Bs;           // [4][128]
  float* rS2 = rS1 + 512;
  int*   rI1 = (int*)(rS2 + 512);
  #pragma unroll
  for (int slot = 0; slot < 16; ++slot) {
    float a1 = s1[slot], a2 = s2v[slot]; int ai = i1[slot];
    #pragma unroll
    for (int off = 1; off < 16; off <<= 1) {
      float b1 = __shfl_xor(a1, off);
      float b2 = __shfl_xor(a2, off);
      int   bi = __shfl_xor(ai, off);
      float mn = fminf(a1, b1);
      a2 = fmaxf(fmaxf(a2, b2), mn);
      if (b1 > a1 || (b1 == a1 && bi < ai)) { a1 = b1; ai = bi; }
    }
    if (c16 == 0) {
      int row = wr * 64 + (slot >> 2) * 16 + q * 4 + (slot & 3);
      rS1[wc * 128 + row] = a1; rS2[wc * 128 + row] = a2; rI1[wc * 128 + row] = ai;
    }
  }
  __syncthreads();
  if (tid < 128) {
    float a1 = rS1[tid], a2 = rS2[tid]; int ai = rI1[tid];
    #pragma unroll
    for (int gq = 1; gq < 4; ++gq) {
      float b1 = rS1[gq * 128 + tid], b2 = rS2[gq * 128 + tid]; int bi = rI1[gq * 128 + tid];
      float mn = fminf(a1, b1);
      a2 = fmaxf(fmaxf(a2, b2), mn);
      if (b1 > a1 || (b1 == a1 && bi < ai)) { a1 = b1; ai = bi; }
    }
    const int row = n0 + tid;
    out_ind[row] = (float)ai;
    if (a1 - a2 < EPS) {
      int p = atomicAdd(cnt, 1);
      list[p] = row;
      flags[row] = p + 1;
    } else {
      flags[row] = 0;
    }
  }
}

// ---------- cleanup: exact fp32 rescore of flagged rows (split 8 k-chunks) ----------
__global__ __launch_bounds__(256) void cleanup_kernel(const float* __restrict__ x,
                                                      const float* __restrict__ embed,
                                                      const float* __restrict__ esq,
                                                      const float* __restrict__ inv2,
                                                      const int* __restrict__ list,
                                                      const int* __restrict__ cnt,
                                                      float2* __restrict__ exact) {
  __shared__ float xr[DDIM];
  __shared__ float red_s[4];
  __shared__ int   red_i[4];
  const int rs = blockIdx.x & 31, kc = blockIdx.x >> 5;
  const int tid = threadIdx.x;
  const int lane = tid & 63, wid = tid >> 6;
  const int n = *cnt;
  for (int ii = rs; ii < n; ii += 32) {
    const int row = list[ii];
    __syncthreads();
    if (tid < 128) *(float4*)&xr[tid * 4] = *(const float4*)&x[(size_t)row * DDIM + tid * 4];
    __syncthreads();
    const float iv = inv2[row];
    float bs = -3e38f; int bi = 0;
    for (int cc = 0; cc < 2; ++cc) {
      const int code = kc * 512 + cc * 256 + tid;
      const float4* er = (const float4*)&embed[(size_t)code * DDIM];
      float acc = 0.f;
      for (int d = 0; d < DDIM / 4; ++d) {
        float4 e4 = er[d];
        float4 x4 = *(const float4*)&xr[d * 4];
        acc += x4.x * e4.x + x4.y * e4.y + x4.z * e4.z + x4.w * e4.w;
      }
      float sc = fmaf(acc, iv, -esq[code]);
      if (sc > bs || (sc == bs && code < bi)) { bs = sc; bi = code; }
    }
    #pragma unroll
    for (int off = 1; off < 64; off <<= 1) {
      float b1 = __shfl_xor(bs, off);
      int   b2 = __shfl_xor(bi, off);
      if (b1 > bs || (b1 == bs && b2 < bi)) { bs = b1; bi = b2; }
    }
    if (lane == 0) { red_s[wid] = bs; red_i[wid] = bi; }
    __syncthreads();
    if (tid == 0) {
      for (int ww = 1; ww < 4; ++ww)
        if (red_s[ww] > red_s[0] || (red_s[ww] == red_s[0] && red_i[ww] < red_i[0])) {
          red_s[0] = red_s[ww]; red_i[0] = red_i[ww];
        }
      exact[(size_t)ii * 8 + kc] = make_float2(red_s[0], (float)red_i[0]);
    }
  }
}

// ---------- gather + transpose (merges exact results for flagged rows) ----------
__global__ __launch_bounds__(256) void gather_kernel(const float* __restrict__ embed,
                                                     const int* __restrict__ flags,
                                                     const float2* __restrict__ exact,
                                                     float* __restrict__ out_ind,
                                                     float* __restrict__ out_q) {
  __shared__ int lidx[64];
  __shared__ float trans[64 * 65];
  const int n0 = blockIdx.x * 64;
  const int tid = threadIdx.x;
  if (tid < 64) {
    const int row = n0 + tid;
    const int f = flags[row];
    int idx;
    if (f) {
      float bsv = -3e38f; int bi = 0;
      const float2* e8 = &exact[(size_t)(f - 1) * 8];
      #pragma unroll
      for (int k = 0; k < 8; ++k) {
        float2 t = e8[k];
        int ci = (int)t.y;
        if (t.x > bsv || (t.x == bsv && ci < bi)) { bsv = t.x; bi = ci; }
      }
      idx = bi;
      out_ind[row] = (float)idx;
    } else {
      idx = (int)out_ind[row];
    }
    lidx[tid] = idx;
  }
  __syncthreads();
  const int bb = n0 >> 12;
  const int t0 = n0 & (TT - 1);
  const int w = tid >> 6, lane = tid & 63;
  for (int d0 = 0; d0 < DDIM; d0 += 64) {
    if (d0) __syncthreads();
    #pragma unroll
    for (int qq = 0; qq < 16; ++qq) {
      int tt2 = w * 16 + qq;
      int e = lidx[tt2];
      trans[lane * 65 + tt2] = embed[(size_t)e * DDIM + d0 + lane];
    }
    __syncthreads();
    #pragma unroll
    for (int qq = 0; qq < 4; ++qq) {
      int dl = (tid >> 4) * 4 + qq;
      int t4 = (tid & 15) * 4;
      float4 o;
      o.x = trans[dl * 65 + t4 + 0];
      o.y = trans[dl * 65 + t4 + 1];
      o.z = trans[dl * 65 + t4 + 2];
      o.w = trans[dl * 65 + t4 + 3];
      *(float4*)&out_q[((size_t)bb * DDIM + d0 + dl) * TT + t0 + t4] = o;
    }
  }
}

extern "C" void kernel_launch(void* const* d_in, const int* in_sizes, int n_in,
                              void* d_out, int out_size, void* d_ws, size_t ws_size,
                              hipStream_t stream) {
  const float* x     = (const float*)d_in[0];
  const float* embed = (const float*)d_in[1];
  char* ws = (char*)d_ws;
  short* eb      = (short*)(ws + 33554432);              //  4,194,304 B
  float* esq     = (float*)(ws + 37748736);              //     16,384 B
  float* inv2    = (float*)(ws + 37765120);              //    131,072 B
  int* list      = (int*)(ws + 39993344);                //    131,072 B
  int* flags     = (int*)(ws + 40124416);                //    131,072 B
  float2* exact  = (float2*)(ws + 40255488);             //  2,097,152 B
  int* cnt       = (int*)(ws + 42352640);                //          4 B

  float* out_ind = (float*)d_out;
  float* out_q   = out_ind + NN;

  prep_kernel<<<KK / 4, 256, 0, stream>>>(embed, eb, esq, 0);
  hipMemsetAsync(cnt, 0, 4, stream);
  vq_mfma<<<256, 512, 0, stream>>>(x, eb, esq, inv2, out_ind, flags, list, cnt);
  cleanup_kernel<<<256, 256, 0, stream>>>(x, embed, esq, inv2, list, cnt, exact);
  gather_kernel<<<NN / 64, 256, 0, stream>>>(embed, flags, exact, out_ind, out_q);
}